// Round 3
// baseline (240.893 us; speedup 1.0000x reference)
//
#include <hip/hip_runtime.h>
#include <math.h>

#define V 100000
#define D 256
#define B 32
#define N 128
#define K 100
#define NPOS (B * N)
#define NGROUPS 26            // ceil(101 rows / 4 rows-per-wave-pass)
#define NORM_TERM 11.512925f
#define LOG_K 4.605170186f    // log(100)

// softplus(x) = max(x,0) + log1p(exp(-|x|)) — overflow-safe, fast intrinsics
__device__ __forceinline__ float softplus(float x) {
    return fmaxf(x, 0.f) + __logf(1.f + __expf(-fabsf(x)));
}

// One block (128 threads, 2 waves) per (b,n) position.
// 16 lanes per row, 4 rows in flight per wave: each quarter-wave reads
// 256 contiguous bytes per load instruction (coalesced segments), so a
// wave-level load touches 16 cache lines shared across 4 rows — ~4x fewer
// TA transactions than lane-per-row. Reduction is 4 shuffle steps per
// 4 rows; epilogue uses fast intrinsics.
__global__ __launch_bounds__(128) void nce_kernel(
    const int* __restrict__ target,        // (B*N)
    const int* __restrict__ noise,         // (B*N*K)
    const float* __restrict__ hidden,      // (B*N*D)
    const float* __restrict__ weight,      // (V*D)
    const float* __restrict__ bias,        // (V)
    const float* __restrict__ noise_probs, // (V)
    float* __restrict__ out)
{
    const int pos  = blockIdx.x;
    const int tid  = threadIdx.x;
    const int wave = tid >> 6;       // 0..1
    const int lane = tid & 63;
    const int q    = lane >> 4;      // quarter (row slot) 0..3
    const int ql   = lane & 15;      // lane within quarter

    // Preload this lane's hidden slice: hreg[i] = h[ql*4 + i*64 .. +3]
    const float* __restrict__ hrow = hidden + (size_t)pos * D;
    float4 hreg[4];
    #pragma unroll
    for (int i = 0; i < 4; ++i)
        hreg[i] = *reinterpret_cast<const float4*>(hrow + ql * 4 + i * 64);

    float loss = 0.f;
    for (int g = wave; g < NGROUPS; g += 2) {
        const int r = g * 4 + q;                  // row id 0..103
        const bool is_noise  = (r < K);
        const bool is_target = (r == K);

        int idx = 0;
        if (is_noise)       idx = noise[(size_t)pos * K + r];
        else if (is_target) idx = target[pos];

        const float* __restrict__ wrow = weight + (size_t)idx * D + ql * 4;
        float acc = 0.f;
        #pragma unroll
        for (int i = 0; i < 4; ++i) {
            const float4 w4 = *reinterpret_cast<const float4*>(wrow + i * 64);
            acc = fmaf(w4.x, hreg[i].x, acc);
            acc = fmaf(w4.y, hreg[i].y, acc);
            acc = fmaf(w4.z, hreg[i].z, acc);
            acc = fmaf(w4.w, hreg[i].w, acc);
        }
        // reduce within the 16-lane quarter (xor of bits 0..3 stays inside)
        #pragma unroll
        for (int off = 1; off < 16; off <<= 1)
            acc += __shfl_xor(acc, off, 64);

        const float score = acc + bias[idx] - NORM_TERM;
        float contrib = 0.f;
        if (is_noise)
            contrib = softplus(score - __logf(noise_probs[idx]) - LOG_K);
        else if (is_target)
            contrib = softplus(LOG_K - score);
        if (ql == 0) loss += contrib;   // one lane per quarter contributes
    }

    // only lanes ql==0 (4 per wave) hold nonzero loss: fold quarters
    loss += __shfl_xor(loss, 16, 64);
    loss += __shfl_xor(loss, 32, 64);
    // lane 0 of each wave now has the wave total

    __shared__ float wsum[2];
    if (lane == 0) wsum[wave] = loss;
    __syncthreads();
    if (tid == 0)
        atomicAdd(out, (wsum[0] + wsum[1]) * (1.0f / (float)NPOS));
}

extern "C" void kernel_launch(void* const* d_in, const int* in_sizes, int n_in,
                              void* d_out, int out_size, void* d_ws, size_t ws_size,
                              hipStream_t stream) {
    const int*   target      = (const int*)d_in[0];
    const int*   noise       = (const int*)d_in[1];
    const float* hidden      = (const float*)d_in[2];
    const float* weight      = (const float*)d_in[3];
    const float* bias        = (const float*)d_in[4];
    const float* noise_probs = (const float*)d_in[5];
    float* out = (float*)d_out;

    // d_out is poisoned 0xAA before every launch — zero it for the atomics
    hipMemsetAsync(out, 0, sizeof(float), stream);

    nce_kernel<<<NPOS, 128, 0, stream>>>(target, noise, hidden, weight,
                                         bias, noise_probs, out);
}